// Round 1
// baseline (329.469 us; speedup 1.0000x reference)
//
#include <hip/hip_runtime.h>
#include <stdint.h>

// Problem constants: B=2, CIN=256, COUT=256, H=W=128, K=3, G=4 (deform groups)
#define HW    16384
#define CIN   256
#define COUT  256
#define Hh    128
#define Ww    128
#define OFFC  72        // G*2*K*K
#define NKC   72        // K-chunks of 32: (256*9)/32

typedef __attribute__((ext_vector_type(4))) float  f32x4;
typedef __attribute__((ext_vector_type(8))) __bf16 bf16x8;
typedef unsigned short u16;
typedef unsigned int   u32;

__device__ __forceinline__ u32 f2bf(float f) {           // RNE f32 -> bf16 bits
  u32 u = __builtin_bit_cast(u32, f);
  return (u + 0x7fffu + ((u >> 16) & 1u)) >> 16;
}
__device__ __forceinline__ float bf2f(u32 bits) {
  return __builtin_bit_cast(float, bits << 16);
}

// ---------------------------------------------------------------------------
// K0: swizzle w_deform [256][256][3][3] f32 into fragment-linear bf16:
//     wfrag[kc(72)][nt(16)][lane(64)][j(8)] = B[k = kc*32 + (lane>>4)*8 + j][cout = nt*16 + (lane&15)]
//     with k-order k = ((g*9+t)*64 + cg)  (cg-major within (g,t): coords shared!)
// ---------------------------------------------------------------------------
__global__ __launch_bounds__(256) void k0(const float* __restrict__ wd, u16* __restrict__ wfrag) {
  __shared__ float ws[9216];                    // [16 cout][64 cg][9 t]
  int nt = blockIdx.x & 15;                     // cout tile
  int g  = blockIdx.x >> 4;                     // group == 64-channel block
  const float* src = wd + (size_t)(nt * 16) * 2304 + (size_t)g * 64 * 9;
  #pragma unroll
  for (int r = 0; r < 36; ++r) {                // coalesced: 576 contiguous f32 per cout
    int idx = threadIdx.x + 256 * r;            // 0..9215
    int cl  = idx / 576;
    int rem = idx - cl * 576;                   // cg*9 + t
    ws[cl * 576 + rem] = src[(size_t)cl * 2304 + rem];
  }
  __syncthreads();
  #pragma unroll
  for (int r = 0; r < 36; ++r) {
    int o    = threadIdx.x + 256 * r;
    int j    = o & 7;
    int lane = (o >> 3) & 63;
    int kcl  = o >> 9;                          // 0..17 = (t, half)
    int t = kcl >> 1, half = kcl & 1;
    int n = lane & 15, q = lane >> 4;
    int cg = half * 32 + q * 8 + j;
    float v = ws[n * 576 + cg * 9 + t];
    int kc = (g * 9 + t) * 2 + half;
    wfrag[(size_t)((kc * 16 + nt) * 64 + lane) * 8 + j] = (u16)f2bf(v);
  }
}

// ---------------------------------------------------------------------------
// K1: 1x1 offset conv: off[b][oc(72)][p] = b_offset[oc] + sum_c x[b][c][p] * w_offset[oc][c]
//     Block: 64 contiguous pixels x all 72 oc. x tile via LDS, weights via s_loads.
// ---------------------------------------------------------------------------
__global__ __launch_bounds__(256) void k1(const float* __restrict__ x, const float* __restrict__ wo,
                                          const float* __restrict__ bo, float* __restrict__ off) {
  __shared__ float xs[4096];                    // [64 c][64 px]
  int b  = blockIdx.x >> 8;
  int p0 = (blockIdx.x & 255) << 6;
  int px = threadIdx.x & 63;
  int og = threadIdx.x >> 6;                    // wave-uniform -> scalar weight loads
  int oc0 = og * 18;
  float acc[18];
  #pragma unroll
  for (int o = 0; o < 18; ++o) acc[o] = bo[oc0 + o];
  const float* xb = x + (size_t)b * CIN * HW + p0;
  for (int ci0 = 0; ci0 < CIN; ci0 += 64) {
    __syncthreads();
    #pragma unroll
    for (int r = 0; r < 16; ++r) {
      int idx = threadIdx.x + 256 * r;
      xs[idx] = xb[(size_t)(ci0 + (idx >> 6)) * HW + (idx & 63)];
    }
    __syncthreads();
    #pragma unroll 4
    for (int c = 0; c < 64; ++c) {
      float xv = xs[c * 64 + px];
      const float* wr = wo + (ci0 + c);
      #pragma unroll
      for (int o = 0; o < 18; ++o)
        acc[o] = fmaf(xv, wr[(size_t)(oc0 + o) * CIN], acc[o]);
    }
  }
  float* ob = off + (size_t)b * OFFC * HW + p0 + px;
  #pragma unroll
  for (int o = 0; o < 18; ++o) ob[(size_t)(oc0 + o) * HW] = acc[o];
}

// ---------------------------------------------------------------------------
// K2: fused bilinear-gather + bf16 MFMA GEMM.
//     Block tile: M=64 pixels (contiguous, same image row) x N=256 cout, K=2304 in 72 chunks of 32.
//     Wave w: all 64 px x cout [w*64, w*64+64); gathers px [w*16, w*16+16) into shared A-stage.
// ---------------------------------------------------------------------------
__global__ __launch_bounds__(256) void k2(const float* __restrict__ x, const float* __restrict__ off,
                                          const u16* __restrict__ wfrag, float* __restrict__ out) {
  __shared__ u16 pre[2304 * 8];     // [(g*9+t)(36)][px(64)] : {4x u16 addr, 4x bf16 wgt} = 36.9 KB
  __shared__ u16 astage[2][2048];   // double-buffered A chunk: [px(64)][k(32)] bf16 = 2x4 KB
  int b  = blockIdx.x >> 8;
  int p0 = (blockIdx.x & 255) << 6;
  int h  = p0 >> 7;
  int w0 = p0 & 127;
  int tid  = threadIdx.x;
  int lane = tid & 63;
  int wv   = tid >> 6;
  int n16  = lane & 15;
  int q    = lane >> 4;

  // ---- precompute bilinear table: thread = (g = tid>>6, px = tid&63), loop 9 taps ----
  {
    int px = tid & 63;
    int g  = tid >> 6;
    const float* ob = off + (size_t)b * OFFC * HW + p0 + px;
    float fh = (float)h, fw = (float)(w0 + px);
    #pragma unroll
    for (int t = 0; t < 9; ++t) {
      int ch = (g * 9 + t) * 2;                  // mmcv layout: [g][t][{dy,dx}]
      float dy = ob[(size_t)ch * HW];
      float dx = ob[(size_t)(ch + 1) * HW];
      float yy = fh + (float)(t / 3) - 1.0f + dy;
      float xx = fw + (float)(t % 3) - 1.0f + dx;
      float y0f = floorf(yy), x0f = floorf(xx);
      float fy = yy - y0f, fx = xx - x0f;
      int y0 = (int)y0f, x0 = (int)x0f;
      int y1 = y0 + 1, x1 = x0 + 1;
      float vy0 = (y0 >= 0 && y0 < Hh) ? 1.f : 0.f;
      float vy1 = (y1 >= 0 && y1 < Hh) ? 1.f : 0.f;
      float vx0 = (x0 >= 0 && x0 < Ww) ? 1.f : 0.f;
      float vx1 = (x1 >= 0 && x1 < Ww) ? 1.f : 0.f;
      float w00 = (1.f - fy) * (1.f - fx) * vy0 * vx0;   // zero-pad semantics folded into weights
      float w01 = (1.f - fy) * fx * vy0 * vx1;
      float w10 = fy * (1.f - fx) * vy1 * vx0;
      float w11 = fy * fx * vy1 * vx1;
      int cy0 = min(max(y0, 0), Hh - 1), cy1 = min(max(y1, 0), Hh - 1);
      int cx0 = min(max(x0, 0), Ww - 1), cx1 = min(max(x1, 0), Ww - 1);
      uint4 ev;
      ev.x = (u32)(cy0 * Ww + cx0) | ((u32)(cy0 * Ww + cx1) << 16);
      ev.y = (u32)(cy1 * Ww + cx0) | ((u32)(cy1 * Ww + cx1) << 16);
      ev.z = f2bf(w00) | (f2bf(w01) << 16);
      ev.w = f2bf(w10) | (f2bf(w11) << 16);
      *(uint4*)&pre[((g * 9 + t) * 64 + px) * 8] = ev;
    }
  }

  f32x4 acc[4][4];
  #pragma unroll
  for (int i = 0; i < 4; ++i)
    #pragma unroll
    for (int jj = 0; jj < 4; ++jj)
      acc[i][jj] = (f32x4){0.f, 0.f, 0.f, 0.f};

  const float* xb = x + (size_t)b * CIN * HW;
  int gpx = wv * 16 + n16;                       // pixel this lane gathers for

  // gather chunk kc (32 channels of one (g,t), cg-major) into astage[buf]
  auto gather = [&](int kc, int buf) {
    int gt = kc >> 1;                            // g*9 + t
    int g  = gt / 9;
    uint4 ev = *(const uint4*)&pre[(gt * 64 + gpx) * 8];
    u32 o00 = ev.x & 0xffffu, o01 = ev.x >> 16;
    u32 o10 = ev.y & 0xffffu, o11 = ev.y >> 16;
    float w00 = bf2f(ev.z & 0xffffu), w01 = bf2f(ev.z >> 16);
    float w10 = bf2f(ev.w & 0xffffu), w11 = bf2f(ev.w >> 16);
    const float* p = xb + (size_t)(g * 64 + (kc & 1) * 32 + q * 8) * HW;
    float s[8];
    #pragma unroll
    for (int j = 0; j < 8; ++j) {                // 8 channels share coords: 4 gathers each
      s[j] = w00 * p[o00] + w01 * p[o01] + w10 * p[o10] + w11 * p[o11];
      p += HW;
    }
    uint4 st;
    st.x = f2bf(s[0]) | (f2bf(s[1]) << 16);
    st.y = f2bf(s[2]) | (f2bf(s[3]) << 16);
    st.z = f2bf(s[4]) | (f2bf(s[5]) << 16);
    st.w = f2bf(s[6]) | (f2bf(s[7]) << 16);
    *(uint4*)&astage[buf][gpx * 32 + q * 8] = st;   // b128, conflict-free
  };

  auto compute = [&](int kc, int buf) {
    const u16* wfp = wfrag + (size_t)((kc * 16 + wv * 4) * 64 + lane) * 8;
    bf16x8 bfrag[4];
    #pragma unroll
    for (int i = 0; i < 4; ++i)                   // fragment-linear: 1 coalesced dwordx4 each
      bfrag[i] = __builtin_bit_cast(bf16x8, *(const uint4*)(wfp + i * 512));
    #pragma unroll
    for (int mt = 0; mt < 4; ++mt) {
      bf16x8 af = __builtin_bit_cast(bf16x8, *(const uint4*)&astage[buf][(mt * 16 + n16) * 32 + q * 8]);
      #pragma unroll
      for (int i = 0; i < 4; ++i)
        acc[mt][i] = __builtin_amdgcn_mfma_f32_16x16x32_bf16(af, bfrag[i], acc[mt][i], 0, 0, 0);
    }
  };

  __syncthreads();                                // pre[] ready
  gather(0, 0);
  for (int kc = 0; kc < NKC; ++kc) {
    __syncthreads();                              // prev gather visible; prev reads of other buf done
    if (kc < NKC - 1) gather(kc + 1, (kc + 1) & 1);
    compute(kc, kc & 1);
  }

  // epilogue: D row = px-in-tile = q*4+reg, col = cout = base + n16; ReLU, float4 stores
  float* op = out + (size_t)b * COUT * HW + p0;
  #pragma unroll
  for (int mt = 0; mt < 4; ++mt) {
    #pragma unroll
    for (int i = 0; i < 4; ++i) {
      f32x4 v = acc[mt][i];
      #pragma unroll
      for (int r = 0; r < 4; ++r) v[r] = fmaxf(v[r], 0.f);
      int cout = wv * 64 + i * 16 + n16;
      int pxb  = mt * 16 + q * 4;
      *(f32x4*)(op + (size_t)cout * HW + pxb) = v;
    }
  }
}

// ---------------------------------------------------------------------------
extern "C" void kernel_launch(void* const* d_in, const int* in_sizes, int n_in,
                              void* d_out, int out_size, void* d_ws, size_t ws_size,
                              hipStream_t stream) {
  const float* x  = (const float*)d_in[0];   // [2][256][128][128]
  const float* wo = (const float*)d_in[1];   // [72][256]
  const float* bo = (const float*)d_in[2];   // [72]
  const float* wd = (const float*)d_in[3];   // [256][256][3][3]
  float* out = (float*)d_out;

  // workspace: wfrag bf16 (1,179,648 B) | offsets f32 (9,437,184 B)  => 10.6 MB
  u16*   wfrag = (u16*)d_ws;
  float* off   = (float*)((char*)d_ws + 1179648);

  k0<<<64, 256, 0, stream>>>(wd, wfrag);
  k1<<<512, 256, 0, stream>>>(x, wo, bo, off);
  k2<<<512, 256, 0, stream>>>(x, off, wfrag, out);
}

// Round 2
// 278.497 us; speedup vs baseline: 1.1830x; 1.1830x over previous
//
#include <hip/hip_runtime.h>
#include <stdint.h>

// B=2, CIN=256, COUT=256, H=W=128, K=3, G=4
#define HW    16384
#define CIN   256
#define COUT  256
#define Hh    128
#define Ww    128
#define OFFC  72        // G*2*K*K

typedef __attribute__((ext_vector_type(4))) float  f32x4;
typedef __attribute__((ext_vector_type(8))) __bf16 bf16x8;
typedef unsigned short u16;
typedef unsigned int   u32;

__device__ __forceinline__ u32 f2bf(float f) {           // RNE f32 -> bf16 bits
  u32 u = __builtin_bit_cast(u32, f);
  return (u + 0x7fffu + ((u >> 16) & 1u)) >> 16;
}
__device__ __forceinline__ float blo(u32 u) { return __builtin_bit_cast(float, u << 16); }
__device__ __forceinline__ float bhi(u32 u) { return __builtin_bit_cast(float, u & 0xffff0000u); }

// ---------------------------------------------------------------------------
// KT: transpose x [2][256][128][128] f32 -> xt [b*4+g][y*128+x][cg=64] bf16 (NHWC per group)
// ---------------------------------------------------------------------------
__global__ __launch_bounds__(256) void kt(const float* __restrict__ x, u16* __restrict__ xt) {
  __shared__ float xs[64 * 65];
  int bg = blockIdx.x >> 8;                     // b*4+g
  int p0 = (blockIdx.x & 255) << 6;
  const float* src = x + (size_t)bg * 64 * HW + p0;
  #pragma unroll
  for (int r = 0; r < 16; ++r) {
    int idx = threadIdx.x + 256 * r;
    int c = idx >> 6, px = idx & 63;
    xs[c * 65 + px] = src[(size_t)c * HW + px];
  }
  __syncthreads();
  int px = threadIdx.x >> 2, seg = threadIdx.x & 3;
  u32 w[8];
  #pragma unroll
  for (int k = 0; k < 8; ++k) {
    float lo = xs[(seg * 16 + 2 * k) * 65 + px];
    float hi = xs[(seg * 16 + 2 * k + 1) * 65 + px];
    w[k] = f2bf(lo) | (f2bf(hi) << 16);
  }
  u16* dst = xt + ((size_t)bg * HW + p0 + px) * 64 + seg * 16;
  *(uint4*)dst       = make_uint4(w[0], w[1], w[2], w[3]);
  *(uint4*)(dst + 8) = make_uint4(w[4], w[5], w[6], w[7]);
}

// ---------------------------------------------------------------------------
// K0: prepack w_deform -> wfrag[kc(72)][nt(16)][lane(64)][j(8)] bf16
//     kc=(g*9+t)*2+half ; B[k][cout], k-chan cg = half*32 + q*8 + j (cg-major per (g,t))
// ---------------------------------------------------------------------------
__global__ __launch_bounds__(256) void k0(const float* __restrict__ wd, u16* __restrict__ wfrag) {
  __shared__ float ws[9216];                    // [16 cout][64 cg][9 t]
  int nt = blockIdx.x & 15;
  int g  = blockIdx.x >> 4;
  const float* src = wd + (size_t)(nt * 16) * 2304 + (size_t)g * 64 * 9;
  #pragma unroll
  for (int r = 0; r < 36; ++r) {
    int idx = threadIdx.x + 256 * r;
    int cl  = idx / 576;
    int rem = idx - cl * 576;
    ws[cl * 576 + rem] = src[(size_t)cl * 2304 + rem];
  }
  __syncthreads();
  #pragma unroll
  for (int r = 0; r < 36; ++r) {
    int o    = threadIdx.x + 256 * r;
    int j    = o & 7;
    int lane = (o >> 3) & 63;
    int kcl  = o >> 9;
    int t = kcl >> 1, half = kcl & 1;
    int n = lane & 15, q = lane >> 4;
    int cg = half * 32 + q * 8 + j;
    float v = ws[n * 576 + cg * 9 + t];
    int kc = (g * 9 + t) * 2 + half;
    wfrag[(size_t)((kc * 16 + nt) * 64 + lane) * 8 + j] = (u16)f2bf(v);
  }
}

// ---------------------------------------------------------------------------
// K0b: prepack w_offset [72][256] -> wfrag2[kc(8)][nt(5)][lane(64)][j(8)] bf16, oc>=72 zero
// ---------------------------------------------------------------------------
__global__ __launch_bounds__(256) void k0b(const float* __restrict__ wo, u16* __restrict__ wfrag2) {
  int e = blockIdx.x * 256 + threadIdx.x;       // < 20480
  int j = e & 7;
  int lane = (e >> 3) & 63;
  int idx = e >> 9;                             // kc*5+nt
  int kc = idx / 5, nt = idx - 5 * kc;
  int n16 = lane & 15, q = lane >> 4;
  int oc = nt * 16 + n16;
  int c  = kc * 32 + q * 8 + j;
  float v = (oc < OFFC) ? wo[(size_t)oc * CIN + c] : 0.f;
  wfrag2[e] = (u16)f2bf(v);
}

// ---------------------------------------------------------------------------
// K1: offset conv as MFMA GEMM over xt. M=32/wave, N=80 (72 valid), K=256 (8 chunks).
// ---------------------------------------------------------------------------
__global__ __launch_bounds__(256) void k1(const u16* __restrict__ xt, const u16* __restrict__ wfrag2,
                                          const float* __restrict__ bo, float* __restrict__ off) {
  int gw = (blockIdx.x << 2) + (threadIdx.x >> 6);    // 1024 waves
  int lane = threadIdx.x & 63, n16 = lane & 15, q = lane >> 4;
  int b  = gw >> 9;
  int p0 = (gw & 511) << 5;
  f32x4 acc[2][5];
  #pragma unroll
  for (int nt = 0; nt < 5; ++nt) {
    int oc = nt * 16 + n16;
    float bv = (oc < OFFC) ? bo[oc] : 0.f;
    acc[0][nt] = (f32x4){bv, bv, bv, bv};
    acc[1][nt] = (f32x4){bv, bv, bv, bv};
  }
  const u16* xtb = xt + (size_t)b * 4 * HW * 64;
  #pragma unroll 1
  for (int kc = 0; kc < 8; ++kc) {
    int g = kc >> 1;
    bf16x8 af[2];
    #pragma unroll
    for (int mt = 0; mt < 2; ++mt) {
      int p = p0 + mt * 16 + n16;
      af[mt] = __builtin_bit_cast(bf16x8, *(const uint4*)(xtb + ((size_t)g * HW + p) * 64 + (kc & 1) * 32 + q * 8));
    }
    #pragma unroll
    for (int nt = 0; nt < 5; ++nt) {
      bf16x8 bf = __builtin_bit_cast(bf16x8, *(const uint4*)(wfrag2 + (size_t)(((kc * 5 + nt) << 6) + lane) * 8));
      acc[0][nt] = __builtin_amdgcn_mfma_f32_16x16x32_bf16(af[0], bf, acc[0][nt], 0, 0, 0);
      acc[1][nt] = __builtin_amdgcn_mfma_f32_16x16x32_bf16(af[1], bf, acc[1][nt], 0, 0, 0);
    }
  }
  float* ob = off + (size_t)b * OFFC * HW;
  #pragma unroll
  for (int nt = 0; nt < 5; ++nt) {
    int oc = nt * 16 + n16;
    if (oc < OFFC) {
      #pragma unroll
      for (int mt = 0; mt < 2; ++mt)
        *(f32x4*)(ob + (size_t)oc * HW + p0 + mt * 16 + q * 4) = acc[mt][nt];
    }
  }
}

// ---------------------------------------------------------------------------
// K2: wave-autonomous fused bilinear-gather + MFMA. Wave: M=32 px x N=128 cout.
//     No LDS, no barriers. Corners read as dwordx4 (8ch) from NHWC bf16 xt.
// ---------------------------------------------------------------------------
__device__ __forceinline__ void mkpre(float yy, float xx, int* ob, float* wg) {
  float y0f = floorf(yy), x0f = floorf(xx);
  float fy = yy - y0f, fx = xx - x0f;
  int y0 = (int)y0f, x0 = (int)x0f;
  int y1 = y0 + 1, x1 = x0 + 1;
  float vy0 = (y0 >= 0 && y0 < Hh) ? 1.f : 0.f;
  float vy1 = (y1 >= 0 && y1 < Hh) ? 1.f : 0.f;
  float vx0 = (x0 >= 0 && x0 < Ww) ? 1.f : 0.f;
  float vx1 = (x1 >= 0 && x1 < Ww) ? 1.f : 0.f;
  wg[0] = (1.f - fy) * (1.f - fx) * vy0 * vx0;
  wg[1] = (1.f - fy) * fx * vy0 * vx1;
  wg[2] = fy * (1.f - fx) * vy1 * vx0;
  wg[3] = fy * fx * vy1 * vx1;
  int cy0 = min(max(y0, 0), Hh - 1), cy1 = min(max(y1, 0), Hh - 1);
  int cx0 = min(max(x0, 0), Ww - 1), cx1 = min(max(x1, 0), Ww - 1);
  ob[0] = (cy0 * Ww + cx0) << 7;                // byte offset: pixel stride 128 B
  ob[1] = (cy0 * Ww + cx1) << 7;
  ob[2] = (cy1 * Ww + cx0) << 7;
  ob[3] = (cy1 * Ww + cx1) << 7;
}

__device__ __forceinline__ bf16x8 bilerp(uint4 v0, uint4 v1, uint4 v2, uint4 v3,
                                         const float* wg) {
  float w0 = wg[0], w1 = wg[1], w2 = wg[2], w3 = wg[3];
  float s0 = w0 * blo(v0.x) + w1 * blo(v1.x) + w2 * blo(v2.x) + w3 * blo(v3.x);
  float s1 = w0 * bhi(v0.x) + w1 * bhi(v1.x) + w2 * bhi(v2.x) + w3 * bhi(v3.x);
  float s2 = w0 * blo(v0.y) + w1 * blo(v1.y) + w2 * blo(v2.y) + w3 * blo(v3.y);
  float s3 = w0 * bhi(v0.y) + w1 * bhi(v1.y) + w2 * bhi(v2.y) + w3 * bhi(v3.y);
  float s4 = w0 * blo(v0.z) + w1 * blo(v1.z) + w2 * blo(v2.z) + w3 * blo(v3.z);
  float s5 = w0 * bhi(v0.z) + w1 * bhi(v1.z) + w2 * bhi(v2.z) + w3 * bhi(v3.z);
  float s6 = w0 * blo(v0.w) + w1 * blo(v1.w) + w2 * blo(v2.w) + w3 * blo(v3.w);
  float s7 = w0 * bhi(v0.w) + w1 * bhi(v1.w) + w2 * bhi(v2.w) + w3 * bhi(v3.w);
  uint4 r;
  r.x = f2bf(s0) | (f2bf(s1) << 16);
  r.y = f2bf(s2) | (f2bf(s3) << 16);
  r.z = f2bf(s4) | (f2bf(s5) << 16);
  r.w = f2bf(s6) | (f2bf(s7) << 16);
  return __builtin_bit_cast(bf16x8, r);
}

__global__ __launch_bounds__(256, 2) void k2(const u16* __restrict__ xt, const float* __restrict__ off,
                                             const u16* __restrict__ wfrag, float* __restrict__ out) {
  int gw = (blockIdx.x << 2) + (threadIdx.x >> 6);    // 2048 waves
  int lane = threadIdx.x & 63, n16 = lane & 15, q = lane >> 4;
  int nhalf = gw & 1;
  int pt = (gw >> 1) & 511;
  int b  = gw >> 10;
  int p0 = pt << 5;
  int h = p0 >> 7, w0 = p0 & 127;
  const float* offp = off + (size_t)b * OFFC * HW;
  const char*  xtb  = (const char*)xt + (size_t)b * 4 * HW * 128;
  f32x4 acc[2][8];
  #pragma unroll
  for (int mt = 0; mt < 2; ++mt)
    #pragma unroll
    for (int nt = 0; nt < 8; ++nt)
      acc[mt][nt] = (f32x4){0.f, 0.f, 0.f, 0.f};
  float fh  = (float)h;
  float fx0 = (float)(w0 + n16);
  int chb = q * 16;

  // prefetch off for gt=0 (ch = 0,1)
  float dyc0 = offp[p0 + n16];
  float dxc0 = offp[(size_t)HW + p0 + n16];
  float dyc1 = offp[p0 + 16 + n16];
  float dxc1 = offp[(size_t)HW + p0 + 16 + n16];

  #pragma unroll 1
  for (int gt = 0; gt < 36; ++gt) {
    int g = (gt * 57) >> 9;                     // gt/9 for 0..35
    int t = gt - g * 9;
    int i = (t * 683) >> 11;                    // t/3 for 0..8
    int j = t - i * 3;
    const char* xtg = xtb + (size_t)g * HW * 128;
    int   ob[2][4];
    float wg[2][4];
    mkpre(fh + (float)(i - 1) + dyc0, fx0 + (float)(j - 1) + dxc0, ob[0], wg[0]);
    mkpre(fh + (float)(i - 1) + dyc1, fx0 + 16.f + (float)(j - 1) + dxc1, ob[1], wg[1]);

    uint4 c0h0[4], c0h1[4], c1h0[4], c1h1[4];
    #pragma unroll
    for (int cr = 0; cr < 4; ++cr) {
      c0h0[cr] = *(const uint4*)(xtg + ob[0][cr] + chb);
      c0h1[cr] = *(const uint4*)(xtg + ob[0][cr] + chb + 64);
      c1h0[cr] = *(const uint4*)(xtg + ob[1][cr] + chb);
      c1h1[cr] = *(const uint4*)(xtg + ob[1][cr] + chb + 64);
    }
    // prefetch off for gt+1
    if (gt < 35) {
      int ch = (gt + 1) * 2;
      dyc0 = offp[(size_t)ch * HW + p0 + n16];
      dxc0 = offp[(size_t)(ch + 1) * HW + p0 + n16];
      dyc1 = offp[(size_t)ch * HW + p0 + 16 + n16];
      dxc1 = offp[(size_t)(ch + 1) * HW + p0 + 16 + n16];
    }
    #pragma unroll
    for (int half = 0; half < 2; ++half) {
      int kc = gt * 2 + half;
      bf16x8 af0 = half ? bilerp(c0h1[0], c0h1[1], c0h1[2], c0h1[3], wg[0])
                        : bilerp(c0h0[0], c0h0[1], c0h0[2], c0h0[3], wg[0]);
      bf16x8 af1 = half ? bilerp(c1h1[0], c1h1[1], c1h1[2], c1h1[3], wg[1])
                        : bilerp(c1h0[0], c1h0[1], c1h0[2], c1h0[3], wg[1]);
      const u16* wbase = wfrag + ((size_t)(kc * 16 + nhalf * 8) * 64 + lane) * 8;
      #pragma unroll
      for (int nt = 0; nt < 8; ++nt) {
        bf16x8 bf = __builtin_bit_cast(bf16x8, *(const uint4*)(wbase + (size_t)nt * 512));
        acc[0][nt] = __builtin_amdgcn_mfma_f32_16x16x32_bf16(af0, bf, acc[0][nt], 0, 0, 0);
        acc[1][nt] = __builtin_amdgcn_mfma_f32_16x16x32_bf16(af1, bf, acc[1][nt], 0, 0, 0);
      }
    }
  }
  // epilogue: row = mt*16 + q*4 + reg, col = nhalf*128 + nt*16 + n16; ReLU
  float* op = out + (size_t)b * COUT * HW;
  #pragma unroll
  for (int mt = 0; mt < 2; ++mt)
    #pragma unroll
    for (int nt = 0; nt < 8; ++nt) {
      f32x4 v = acc[mt][nt];
      #pragma unroll
      for (int r = 0; r < 4; ++r) v[r] = fmaxf(v[r], 0.f);
      int cout = nhalf * 128 + nt * 16 + n16;
      *(f32x4*)(op + (size_t)cout * HW + p0 + mt * 16 + q * 4) = v;
    }
}

// ---------------------------------------------------------------------------
extern "C" void kernel_launch(void* const* d_in, const int* in_sizes, int n_in,
                              void* d_out, int out_size, void* d_ws, size_t ws_size,
                              hipStream_t stream) {
  const float* x  = (const float*)d_in[0];   // [2][256][128][128]
  const float* wo = (const float*)d_in[1];   // [72][256]
  const float* bo = (const float*)d_in[2];   // [72]
  const float* wd = (const float*)d_in[3];   // [256][256][3][3]
  float* out = (float*)d_out;

  // ws layout (bytes): xt 16,777,216 | wfrag 1,179,648 | wfrag2 40,960 | off 9,437,184
  u16*   xtp    = (u16*)d_ws;
  u16*   wfrag  = (u16*)((char*)d_ws + 16777216);
  u16*   wfrag2 = (u16*)((char*)d_ws + 16777216 + 1179648);
  float* off    = (float*)((char*)d_ws + 16777216 + 1179648 + 40960);

  kt <<<2048, 256, 0, stream>>>(x, xtp);
  k0 <<<64,   256, 0, stream>>>(wd, wfrag);
  k0b<<<80,   256, 0, stream>>>(wo, wfrag2);
  k1 <<<256,  256, 0, stream>>>(xtp, wfrag2, bo, off);
  k2 <<<512,  256, 0, stream>>>(xtp, off, wfrag, out);
}

// Round 3
// 240.368 us; speedup vs baseline: 1.3707x; 1.1586x over previous
//
#include <hip/hip_runtime.h>
#include <stdint.h>

// B=2, CIN=256, COUT=256, H=W=128, K=3, G=4
#define HW    16384
#define CIN   256
#define COUT  256
#define Hh    128
#define Ww    128
#define OFFC  72        // G*2*K*K

typedef __attribute__((ext_vector_type(4))) float  f32x4;
typedef __attribute__((ext_vector_type(8))) __bf16 bf16x8;
typedef unsigned short u16;
typedef unsigned int   u32;

__device__ __forceinline__ u32 f2bf(float f) {           // RNE f32 -> bf16 bits
  u32 u = __builtin_bit_cast(u32, f);
  return (u + 0x7fffu + ((u >> 16) & 1u)) >> 16;
}
__device__ __forceinline__ float blo(u32 u) { return __builtin_bit_cast(float, u << 16); }
__device__ __forceinline__ float bhi(u32 u) { return __builtin_bit_cast(float, u & 0xffff0000u); }

// ---------------------------------------------------------------------------
// KT: transpose x [2][256][128][128] f32 -> xt [b*4+g][y*128+x][cg=64] bf16
// ---------------------------------------------------------------------------
__global__ __launch_bounds__(256) void kt(const float* __restrict__ x, u16* __restrict__ xt) {
  __shared__ float xs[64 * 65];
  int bg = blockIdx.x >> 8;
  int p0 = (blockIdx.x & 255) << 6;
  const float* src = x + (size_t)bg * 64 * HW + p0;
  #pragma unroll
  for (int r = 0; r < 16; ++r) {
    int idx = threadIdx.x + 256 * r;
    int c = idx >> 6, px = idx & 63;
    xs[c * 65 + px] = src[(size_t)c * HW + px];
  }
  __syncthreads();
  int px = threadIdx.x >> 2, seg = threadIdx.x & 3;
  u32 w[8];
  #pragma unroll
  for (int k = 0; k < 8; ++k) {
    float lo = xs[(seg * 16 + 2 * k) * 65 + px];
    float hi = xs[(seg * 16 + 2 * k + 1) * 65 + px];
    w[k] = f2bf(lo) | (f2bf(hi) << 16);
  }
  u16* dst = xt + ((size_t)bg * HW + p0 + px) * 64 + seg * 16;
  *(uint4*)dst       = make_uint4(w[0], w[1], w[2], w[3]);
  *(uint4*)(dst + 8) = make_uint4(w[4], w[5], w[6], w[7]);
}

// ---------------------------------------------------------------------------
// K0: prepack w_deform -> wfrag[kc(72)][nt(16)][lane(64)][j(8)] bf16
// ---------------------------------------------------------------------------
__global__ __launch_bounds__(256) void k0(const float* __restrict__ wd, u16* __restrict__ wfrag) {
  __shared__ float ws[9216];
  int nt = blockIdx.x & 15;
  int g  = blockIdx.x >> 4;
  const float* src = wd + (size_t)(nt * 16) * 2304 + (size_t)g * 64 * 9;
  #pragma unroll
  for (int r = 0; r < 36; ++r) {
    int idx = threadIdx.x + 256 * r;
    int cl  = idx / 576;
    int rem = idx - cl * 576;
    ws[cl * 576 + rem] = src[(size_t)cl * 2304 + rem];
  }
  __syncthreads();
  #pragma unroll
  for (int r = 0; r < 36; ++r) {
    int o    = threadIdx.x + 256 * r;
    int j    = o & 7;
    int lane = (o >> 3) & 63;
    int kcl  = o >> 9;
    int t = kcl >> 1, half = kcl & 1;
    int n = lane & 15, q = lane >> 4;
    int cg = half * 32 + q * 8 + j;
    float v = ws[n * 576 + cg * 9 + t];
    int kc = (g * 9 + t) * 2 + half;
    wfrag[(size_t)((kc * 16 + nt) * 64 + lane) * 8 + j] = (u16)f2bf(v);
  }
}

// ---------------------------------------------------------------------------
// K0b: prepack w_offset [72][256] -> wfrag2[kc(8)][nt(5)][lane(64)][j(8)] bf16
// ---------------------------------------------------------------------------
__global__ __launch_bounds__(256) void k0b(const float* __restrict__ wo, u16* __restrict__ wfrag2) {
  int e = blockIdx.x * 256 + threadIdx.x;       // < 20480
  int j = e & 7;
  int lane = (e >> 3) & 63;
  int idx = e >> 9;
  int kc = idx / 5, nt = idx - 5 * kc;
  int n16 = lane & 15, q = lane >> 4;
  int oc = nt * 16 + n16;
  int c  = kc * 32 + q * 8 + j;
  float v = (oc < OFFC) ? wo[(size_t)oc * CIN + c] : 0.f;
  wfrag2[e] = (u16)f2bf(v);
}

// ---------------------------------------------------------------------------
// K1: offset conv MFMA GEMM. M=16/wave, N=80 (72 valid), K=256. 2048 waves.
// ---------------------------------------------------------------------------
__global__ __launch_bounds__(256) void k1(const u16* __restrict__ xt, const u16* __restrict__ wfrag2,
                                          const float* __restrict__ bo, float* __restrict__ off) {
  int gw = (blockIdx.x << 2) + (threadIdx.x >> 6);    // 2048 waves
  int lane = threadIdx.x & 63, n16 = lane & 15, q = lane >> 4;
  int b  = gw >> 10;
  int p0 = (gw & 1023) << 4;
  f32x4 acc[5];
  #pragma unroll
  for (int nt = 0; nt < 5; ++nt) {
    int oc = nt * 16 + n16;
    float bv = (oc < OFFC) ? bo[oc] : 0.f;
    acc[nt] = (f32x4){bv, bv, bv, bv};
  }
  const u16* xtb = xt + (size_t)b * 4 * HW * 64;
  #pragma unroll
  for (int kc = 0; kc < 8; ++kc) {
    int g = kc >> 1;
    bf16x8 af = __builtin_bit_cast(bf16x8,
        *(const uint4*)(xtb + ((size_t)g * HW + p0 + n16) * 64 + (kc & 1) * 32 + q * 8));
    #pragma unroll
    for (int nt = 0; nt < 5; ++nt) {
      bf16x8 bf = __builtin_bit_cast(bf16x8, *(const uint4*)(wfrag2 + (size_t)(((kc * 5 + nt) << 6) + lane) * 8));
      acc[nt] = __builtin_amdgcn_mfma_f32_16x16x32_bf16(af, bf, acc[nt], 0, 0, 0);
    }
  }
  float* ob = off + (size_t)b * OFFC * HW;
  #pragma unroll
  for (int nt = 0; nt < 5; ++nt) {
    int oc = nt * 16 + n16;
    if (oc < OFFC)
      *(f32x4*)(ob + (size_t)oc * HW + p0 + q * 4) = acc[nt];
  }
}

// ---------------------------------------------------------------------------
// K2: producer/consumer fused DCN. Block = 4 waves, px tile 32, N=256.
//     Wave (s,n): produces A-half h=n of subtile s (gather+bilerp -> LDS),
//     consumes A(subtile s, both halves) x B(nhalf n). Double-buffered LDS,
//     one barrier/gt, corners for gt+1 issued before consuming gt.
// ---------------------------------------------------------------------------
__device__ __forceinline__ void mkpre(float yy, float xx, int* ob, float* wg) {
  float y0f = floorf(yy), x0f = floorf(xx);
  float fy = yy - y0f, fx = xx - x0f;
  int y0 = (int)y0f, x0 = (int)x0f;
  int y1 = y0 + 1, x1 = x0 + 1;
  float vy0 = (y0 >= 0 && y0 < Hh) ? 1.f : 0.f;
  float vy1 = (y1 >= 0 && y1 < Hh) ? 1.f : 0.f;
  float vx0 = (x0 >= 0 && x0 < Ww) ? 1.f : 0.f;
  float vx1 = (x1 >= 0 && x1 < Ww) ? 1.f : 0.f;
  wg[0] = (1.f - fy) * (1.f - fx) * vy0 * vx0;
  wg[1] = (1.f - fy) * fx * vy0 * vx1;
  wg[2] = fy * (1.f - fx) * vy1 * vx0;
  wg[3] = fy * fx * vy1 * vx1;
  int cy0 = min(max(y0, 0), Hh - 1), cy1 = min(max(y1, 0), Hh - 1);
  int cx0 = min(max(x0, 0), Ww - 1), cx1 = min(max(x1, 0), Ww - 1);
  ob[0] = (cy0 * Ww + cx0) << 7;
  ob[1] = (cy0 * Ww + cx1) << 7;
  ob[2] = (cy1 * Ww + cx0) << 7;
  ob[3] = (cy1 * Ww + cx1) << 7;
}

__device__ __forceinline__ uint4 bilerp(uint4 v0, uint4 v1, uint4 v2, uint4 v3, const float* wg) {
  float w0 = wg[0], w1 = wg[1], w2 = wg[2], w3 = wg[3];
  float s0 = w0 * blo(v0.x) + w1 * blo(v1.x) + w2 * blo(v2.x) + w3 * blo(v3.x);
  float s1 = w0 * bhi(v0.x) + w1 * bhi(v1.x) + w2 * bhi(v2.x) + w3 * bhi(v3.x);
  float s2 = w0 * blo(v0.y) + w1 * blo(v1.y) + w2 * blo(v2.y) + w3 * blo(v3.y);
  float s3 = w0 * bhi(v0.y) + w1 * bhi(v1.y) + w2 * bhi(v2.y) + w3 * bhi(v3.y);
  float s4 = w0 * blo(v0.z) + w1 * blo(v1.z) + w2 * blo(v2.z) + w3 * blo(v3.z);
  float s5 = w0 * bhi(v0.z) + w1 * bhi(v1.z) + w2 * bhi(v2.z) + w3 * bhi(v3.z);
  float s6 = w0 * blo(v0.w) + w1 * blo(v1.w) + w2 * blo(v2.w) + w3 * blo(v3.w);
  float s7 = w0 * bhi(v0.w) + w1 * bhi(v1.w) + w2 * bhi(v2.w) + w3 * bhi(v3.w);
  uint4 r;
  r.x = f2bf(s0) | (f2bf(s1) << 16);
  r.y = f2bf(s2) | (f2bf(s3) << 16);
  r.z = f2bf(s4) | (f2bf(s5) << 16);
  r.w = f2bf(s6) | (f2bf(s7) << 16);
  return r;
}

__global__ __launch_bounds__(256, 4) void k2(const u16* __restrict__ xt, const float* __restrict__ off,
                                             const u16* __restrict__ wfrag, float* __restrict__ out) {
  __shared__ u16 astage[4096];                  // [buf2][s2][h2][lane64][8] = 8 KB
  int tid = threadIdx.x;
  int lane = tid & 63, n16 = lane & 15, q = lane >> 4;
  int wv = tid >> 6;
  int s = wv >> 1, n = wv & 1;                  // subtile, (produced-half / consumed-nhalf)
  int b  = blockIdx.x >> 9;
  int p0 = (blockIdx.x & 511) << 5;
  int h  = p0 >> 7, w0 = p0 & 127;
  int px = p0 + s * 16 + n16;                   // this lane's pixel (linear index)
  float fh = (float)h;
  float fx = (float)(w0 + s * 16 + n16);
  const float* offp = off + (size_t)b * OFFC * HW;
  const char*  xtb  = (const char*)xt + (size_t)b * 4 * HW * 128;
  int chb = n * 64 + q * 16;                    // byte offset within 128B pixel record

  f32x4 acc[8];
  #pragma unroll
  for (int nt = 0; nt < 8; ++nt) acc[nt] = (f32x4){0.f, 0.f, 0.f, 0.f};

  // ---- prologue: offsets for gt=0,1; produce gt=0 ----
  float dy1, dx1;
  {
    float dy0 = offp[px];
    float dx0 = offp[(size_t)HW + px];
    dy1 = offp[(size_t)2 * HW + px];
    dx1 = offp[(size_t)3 * HW + px];
    int ob[4]; float wg[4];
    mkpre(fh - 1.f + dy0, fx - 1.f + dx0, ob, wg);          // gt=0: g=0,t=0 -> i-1=-1, j-1=-1
    uint4 c0 = *(const uint4*)(xtb + ob[0] + chb);
    uint4 c1 = *(const uint4*)(xtb + ob[1] + chb);
    uint4 c2 = *(const uint4*)(xtb + ob[2] + chb);
    uint4 c3 = *(const uint4*)(xtb + ob[3] + chb);
    uint4 fr = bilerp(c0, c1, c2, c3, wg);
    *(uint4*)&astage[(size_t)((s * 2 + n) << 9) + lane * 8] = fr;   // buf 0
  }
  __syncthreads();

  #pragma unroll 1
  for (int gt = 0; gt < 36; ++gt) {
    int buf = gt & 1;
    // ---- stage gt+1: mkpre + issue corner loads (latency hidden by consume) ----
    uint4 d0, d1, d2, d3;
    float wg[4];
    if (gt < 35) {
      int gtn = gt + 1;
      int g1 = (gtn * 57) >> 9;                 // gtn/9
      int t  = gtn - g1 * 9;
      int i  = (t * 683) >> 11;                 // t/3
      int j  = t - i * 3;
      int ob[4];
      mkpre(fh + (float)(i - 1) + dy1, fx + (float)(j - 1) + dx1, ob, wg);
      const char* xg = xtb + (size_t)g1 * HW * 128;
      d0 = *(const uint4*)(xg + ob[0] + chb);
      d1 = *(const uint4*)(xg + ob[1] + chb);
      d2 = *(const uint4*)(xg + ob[2] + chb);
      d3 = *(const uint4*)(xg + ob[3] + chb);
      if (gt < 34) {                            // prefetch offsets for gt+2
        dy1 = offp[(size_t)(2 * gt + 4) * HW + px];
        dx1 = offp[(size_t)(2 * gt + 5) * HW + px];
      }
    }
    // ---- consume gt: A from LDS (both halves), B = nhalf n ----
    #pragma unroll
    for (int hh = 0; hh < 2; ++hh) {
      int kc = gt * 2 + hh;
      bf16x8 af = __builtin_bit_cast(bf16x8,
          *(const uint4*)&astage[(size_t)(((buf << 2) + (s << 1) + hh) << 9) + lane * 8]);
      const u16* wbase = wfrag + ((size_t)(kc * 16 + n * 8) * 64 + lane) * 8;
      #pragma unroll
      for (int nt = 0; nt < 8; ++nt) {
        bf16x8 bfr = __builtin_bit_cast(bf16x8, *(const uint4*)(wbase + (size_t)nt * 512));
        acc[nt] = __builtin_amdgcn_mfma_f32_16x16x32_bf16(af, bfr, acc[nt], 0, 0, 0);
      }
    }
    // ---- produce gt+1 into other buffer, then barrier ----
    if (gt < 35) {
      uint4 fr = bilerp(d0, d1, d2, d3, wg);
      *(uint4*)&astage[(size_t)((((buf ^ 1) << 2) + (s << 1) + n) << 9) + lane * 8] = fr;
      __syncthreads();
    }
  }

  // ---- epilogue: row = q*4+reg (px), col = n*128 + nt*16 + n16 (cout); ReLU ----
  float* op = out + (size_t)b * COUT * HW + p0 + s * 16 + q * 4;
  #pragma unroll
  for (int nt = 0; nt < 8; ++nt) {
    f32x4 v = acc[nt];
    #pragma unroll
    for (int r = 0; r < 4; ++r) v[r] = fmaxf(v[r], 0.f);
    int cout = n * 128 + nt * 16 + n16;
    *(f32x4*)(op + (size_t)cout * HW) = v;
  }
}

// ---------------------------------------------------------------------------
extern "C" void kernel_launch(void* const* d_in, const int* in_sizes, int n_in,
                              void* d_out, int out_size, void* d_ws, size_t ws_size,
                              hipStream_t stream) {
  const float* x  = (const float*)d_in[0];
  const float* wo = (const float*)d_in[1];
  const float* bo = (const float*)d_in[2];
  const float* wd = (const float*)d_in[3];
  float* out = (float*)d_out;

  // ws: xt 16,777,216 | wfrag 1,179,648 | wfrag2 40,960 | off 9,437,184
  u16*   xtp    = (u16*)d_ws;
  u16*   wfrag  = (u16*)((char*)d_ws + 16777216);
  u16*   wfrag2 = (u16*)((char*)d_ws + 16777216 + 1179648);
  float* off    = (float*)((char*)d_ws + 16777216 + 1179648 + 40960);

  kt <<<2048, 256, 0, stream>>>(x, xtp);
  k0 <<<64,   256, 0, stream>>>(wd, wfrag);
  k0b<<<80,   256, 0, stream>>>(wo, wfrag2);
  k1 <<<512,  256, 0, stream>>>(xtp, wfrag2, bo, off);
  k2 <<<1024, 256, 0, stream>>>(xtp, off, wfrag, out);
}

// Round 4
// 198.417 us; speedup vs baseline: 1.6605x; 1.2114x over previous
//
#include <hip/hip_runtime.h>
#include <stdint.h>

// B=2, CIN=256, COUT=256, H=W=128, K=3, G=4
#define HW    16384
#define CIN   256
#define COUT  256
#define Hh    128
#define Ww    128
#define OFFC  72        // G*2*K*K

typedef __attribute__((ext_vector_type(4))) float    f32x4;
typedef __attribute__((ext_vector_type(2))) _Float16 f16x2;
typedef __attribute__((ext_vector_type(8))) _Float16 f16x8;
typedef unsigned short u16;
typedef unsigned int   u32;

__device__ __forceinline__ u16 f2h(float f) { return __builtin_bit_cast(u16, (_Float16)f); }
__device__ __forceinline__ u32 pk2(float f) { u32 h = f2h(f); return h | (h << 16); }
__device__ __forceinline__ f16x2 bch(u32 u) { return __builtin_bit_cast(f16x2, u); }

// ---------------------------------------------------------------------------
// KPREP: fused {kt: x f32 NCHW -> xt f16 [b*4+g][px][64]} + {k0: w_deform ->
// wfrag f16 [kc72][nt16][lane64][j8]} + {k0b: w_offset -> wfrag2 f16}
// ---------------------------------------------------------------------------
__global__ __launch_bounds__(256) void kprep(const float* __restrict__ x, const float* __restrict__ wd,
                                             const float* __restrict__ wo, u16* __restrict__ xt,
                                             u16* __restrict__ wfrag, u16* __restrict__ wfrag2) {
  __shared__ float smem[9216];
  int blk = blockIdx.x;
  if (blk < 2048) {                             // ---- kt: transpose to NHWC f16 ----
    int bg = blk >> 8;
    int p0 = (blk & 255) << 6;
    const float* src = x + (size_t)bg * 64 * HW + p0;
    #pragma unroll
    for (int r = 0; r < 16; ++r) {
      int idx = threadIdx.x + 256 * r;
      int c = idx >> 6, px = idx & 63;
      smem[c * 65 + px] = src[(size_t)c * HW + px];
    }
    __syncthreads();
    int px = threadIdx.x >> 2, seg = threadIdx.x & 3;
    u32 w[8];
    #pragma unroll
    for (int k = 0; k < 8; ++k) {
      float lo = smem[(seg * 16 + 2 * k) * 65 + px];
      float hi = smem[(seg * 16 + 2 * k + 1) * 65 + px];
      w[k] = (u32)f2h(lo) | ((u32)f2h(hi) << 16);
    }
    u16* dst = xt + ((size_t)bg * HW + p0 + px) * 64 + seg * 16;
    *(uint4*)dst       = make_uint4(w[0], w[1], w[2], w[3]);
    *(uint4*)(dst + 8) = make_uint4(w[4], w[5], w[6], w[7]);
  } else if (blk < 2112) {                      // ---- k0: w_deform prepack ----
    int bb = blk - 2048;
    int nt = bb & 15;
    int g  = bb >> 4;
    const float* src = wd + (size_t)(nt * 16) * 2304 + (size_t)g * 64 * 9;
    #pragma unroll
    for (int r = 0; r < 36; ++r) {
      int idx = threadIdx.x + 256 * r;
      int cl  = idx / 576;
      int rem = idx - cl * 576;
      smem[cl * 576 + rem] = src[(size_t)cl * 2304 + rem];
    }
    __syncthreads();
    #pragma unroll
    for (int r = 0; r < 36; ++r) {
      int o    = threadIdx.x + 256 * r;
      int j    = o & 7;
      int lane = (o >> 3) & 63;
      int kcl  = o >> 9;
      int t = kcl >> 1, half = kcl & 1;
      int n = lane & 15, q = lane >> 4;
      int cg = half * 32 + q * 8 + j;
      float v = smem[n * 576 + cg * 9 + t];
      int kc = (g * 9 + t) * 2 + half;
      wfrag[(size_t)((kc * 16 + nt) * 64 + lane) * 8 + j] = f2h(v);
    }
  } else {                                      // ---- k0b: w_offset prepack ----
    int e = (blk - 2112) * 256 + threadIdx.x;   // < 20480
    int j = e & 7;
    int lane = (e >> 3) & 63;
    int idx = e >> 9;
    int kc = idx / 5, nt = idx - 5 * kc;
    int n16 = lane & 15, q = lane >> 4;
    int oc = nt * 16 + n16;
    int c  = kc * 32 + q * 8 + j;
    float v = (oc < OFFC) ? wo[(size_t)oc * CIN + c] : 0.f;
    wfrag2[e] = f2h(v);
  }
}

// ---------------------------------------------------------------------------
// K1: offset conv MFMA GEMM (f16). M=16/wave, N=80 (72 valid), K=256.
// ---------------------------------------------------------------------------
__global__ __launch_bounds__(256) void k1(const u16* __restrict__ xt, const u16* __restrict__ wfrag2,
                                          const float* __restrict__ bo, float* __restrict__ off) {
  int gw = (blockIdx.x << 2) + (threadIdx.x >> 6);    // 2048 waves
  int lane = threadIdx.x & 63, n16 = lane & 15, q = lane >> 4;
  int b  = gw >> 10;
  int p0 = (gw & 1023) << 4;
  f32x4 acc[5];
  #pragma unroll
  for (int nt = 0; nt < 5; ++nt) {
    int oc = nt * 16 + n16;
    float bv = (oc < OFFC) ? bo[oc] : 0.f;
    acc[nt] = (f32x4){bv, bv, bv, bv};
  }
  const u16* xtb = xt + (size_t)b * 4 * HW * 64;
  #pragma unroll
  for (int kc = 0; kc < 8; ++kc) {
    int g = kc >> 1;
    f16x8 af = __builtin_bit_cast(f16x8,
        *(const uint4*)(xtb + ((size_t)g * HW + p0 + n16) * 64 + (kc & 1) * 32 + q * 8));
    #pragma unroll
    for (int nt = 0; nt < 5; ++nt) {
      f16x8 bf = __builtin_bit_cast(f16x8, *(const uint4*)(wfrag2 + (size_t)(((kc * 5 + nt) << 6) + lane) * 8));
      acc[nt] = __builtin_amdgcn_mfma_f32_16x16x32_f16(af, bf, acc[nt], 0, 0, 0);
    }
  }
  float* ob = off + (size_t)b * OFFC * HW;
  #pragma unroll
  for (int nt = 0; nt < 5; ++nt) {
    int oc = nt * 16 + n16;
    if (oc < OFFC)
      *(f32x4*)(ob + (size_t)oc * HW + p0 + q * 4) = acc[nt];
  }
}

// ---------------------------------------------------------------------------
// K2: fused DCN. Block = 4 waves, M=64 px x N=256 cout, K looped over 36 gt.
//     Wave wv: produces A subtile s=wv (both 32-ch halves: gather+pk-f16
//     bilerp -> LDS), consumes all 4 subtiles x cout quarter n=wv. acc[4][4].
//     Double-buffered LDS, one barrier/gt, gt+1 gathers issued before consume.
// ---------------------------------------------------------------------------
__device__ __forceinline__ void mkpre(float yy, float xx, int* ob, u32* wp) {
  float y0f = floorf(yy), x0f = floorf(xx);
  float fy = yy - y0f, fx = xx - x0f;
  int y0 = (int)y0f, x0 = (int)x0f;
  int y1 = y0 + 1, x1 = x0 + 1;
  float vy0 = (y0 >= 0 && y0 < Hh) ? 1.f : 0.f;
  float vy1 = (y1 >= 0 && y1 < Hh) ? 1.f : 0.f;
  float vx0 = (x0 >= 0 && x0 < Ww) ? 1.f : 0.f;
  float vx1 = (x1 >= 0 && x1 < Ww) ? 1.f : 0.f;
  wp[0] = pk2((1.f - fy) * (1.f - fx) * vy0 * vx0);   // zero-pad folded into weights
  wp[1] = pk2((1.f - fy) * fx * vy0 * vx1);
  wp[2] = pk2(fy * (1.f - fx) * vy1 * vx0);
  wp[3] = pk2(fy * fx * vy1 * vx1);
  int cy0 = min(max(y0, 0), Hh - 1), cy1 = min(max(y1, 0), Hh - 1);
  int cx0 = min(max(x0, 0), Ww - 1), cx1 = min(max(x1, 0), Ww - 1);
  ob[0] = (cy0 * Ww + cx0) << 7;                // byte offsets, 128 B pixel records
  ob[1] = (cy0 * Ww + cx1) << 7;
  ob[2] = (cy1 * Ww + cx0) << 7;
  ob[3] = (cy1 * Ww + cx1) << 7;
}

__device__ __forceinline__ uint4 bil16(uint4 a, uint4 b, uint4 c, uint4 d, const u32* wp) {
  f16x2 W0 = bch(wp[0]), W1 = bch(wp[1]), W2 = bch(wp[2]), W3 = bch(wp[3]);
  uint4 r;
  { f16x2 s = bch(a.x) * W0 + bch(b.x) * W1 + bch(c.x) * W2 + bch(d.x) * W3; r.x = __builtin_bit_cast(u32, s); }
  { f16x2 s = bch(a.y) * W0 + bch(b.y) * W1 + bch(c.y) * W2 + bch(d.y) * W3; r.y = __builtin_bit_cast(u32, s); }
  { f16x2 s = bch(a.z) * W0 + bch(b.z) * W1 + bch(c.z) * W2 + bch(d.z) * W3; r.z = __builtin_bit_cast(u32, s); }
  { f16x2 s = bch(a.w) * W0 + bch(b.w) * W1 + bch(c.w) * W2 + bch(d.w) * W3; r.w = __builtin_bit_cast(u32, s); }
  return r;
}

__global__ __launch_bounds__(256, 2) void k2(const u16* __restrict__ xt, const float* __restrict__ off,
                                             const u16* __restrict__ wfrag, float* __restrict__ out) {
  __shared__ u16 astage[8192];                  // [buf2][s4][h2][lane64][8] f16 = 16 KB
  int tid = threadIdx.x;
  int lane = tid & 63, n16 = lane & 15, q = tid >> 4 & 3;
  int wv = tid >> 6;
  int b  = blockIdx.x >> 8;                     // 512 blocks: 256/image
  int p0 = (blockIdx.x & 255) << 6;             // 64-px tile, single row
  int h  = p0 >> 7, w0 = p0 & 127;
  int pxg = p0 + wv * 16 + n16;                 // pixel this lane gathers for
  float fh = (float)h;
  float fx = (float)(w0 + wv * 16 + n16);
  const float* offp = off + (size_t)b * OFFC * HW;
  const char*  xtb  = (const char*)xt + (size_t)b * 4 * HW * 128;
  int chb = q * 16;                             // half0 byte offset in record; half1 = +64

  f32x4 acc[4][4];
  #pragma unroll
  for (int mt = 0; mt < 4; ++mt)
    #pragma unroll
    for (int j = 0; j < 4; ++j) acc[mt][j] = (f32x4){0.f, 0.f, 0.f, 0.f};

  // ---- prologue: offsets gt=0,1; produce gt=0 into buf 0 ----
  float dy1, dx1;
  {
    float dy0 = offp[pxg];
    float dx0 = offp[(size_t)HW + pxg];
    dy1 = offp[(size_t)2 * HW + pxg];
    dx1 = offp[(size_t)3 * HW + pxg];
    int ob[4]; u32 wp[4];
    mkpre(fh - 1.f + dy0, fx - 1.f + dx0, ob, wp);          // gt=0: g=0,t=0
    uint4 c0[4], c1[4];
    #pragma unroll
    for (int c = 0; c < 4; ++c) {
      c0[c] = *(const uint4*)(xtb + ob[c] + chb);
      c1[c] = *(const uint4*)(xtb + ob[c] + chb + 64);
    }
    *(uint4*)&astage[(wv * 2 + 0) * 512 + lane * 8] = bil16(c0[0], c0[1], c0[2], c0[3], wp);
    *(uint4*)&astage[(wv * 2 + 1) * 512 + lane * 8] = bil16(c1[0], c1[1], c1[2], c1[3], wp);
  }
  __syncthreads();

  #pragma unroll 1
  for (int gt = 0; gt < 36; ++gt) {
    int buf = gt & 1;
    // ---- issue gathers for gt+1 (latency hidden behind consume) ----
    uint4 d0[4], d1[4];
    u32 wp[4];
    if (gt < 35) {
      int gtn = gt + 1;
      int g1 = (gtn * 57) >> 9;                 // gtn/9
      int t  = gtn - g1 * 9;
      int i  = (t * 683) >> 11;                 // t/3
      int j  = t - i * 3;
      int ob[4];
      mkpre(fh + (float)(i - 1) + dy1, fx + (float)(j - 1) + dx1, ob, wp);
      const char* xg = xtb + (size_t)g1 * HW * 128;
      #pragma unroll
      for (int c = 0; c < 4; ++c) {
        d0[c] = *(const uint4*)(xg + ob[c] + chb);
        d1[c] = *(const uint4*)(xg + ob[c] + chb + 64);
      }
      if (gt < 34) {                            // offsets for gt+2
        dy1 = offp[(size_t)(2 * gt + 4) * HW + pxg];
        dx1 = offp[(size_t)(2 * gt + 5) * HW + pxg];
      }
    }
    // ---- consume gt: A all 4 subtiles from LDS, B = cout quarter wv ----
    const u16* wb = wfrag + ((size_t)((gt * 2) * 16 + wv * 4) * 64 + lane) * 8;
    f16x8 af[4][2];
    uint4 bf[2][4];
    #pragma unroll
    for (int hh = 0; hh < 2; ++hh) {
      #pragma unroll
      for (int j = 0; j < 4; ++j)
        bf[hh][j] = *(const uint4*)(wb + (size_t)(hh * 16 + j) * 512);
      #pragma unroll
      for (int mt = 0; mt < 4; ++mt)
        af[mt][hh] = __builtin_bit_cast(f16x8,
            *(const uint4*)&astage[(buf * 8 + mt * 2 + hh) * 512 + lane * 8]);
    }
    #pragma unroll
    for (int hh = 0; hh < 2; ++hh)
      #pragma unroll
      for (int mt = 0; mt < 4; ++mt)
        #pragma unroll
        for (int j = 0; j < 4; ++j)
          acc[mt][j] = __builtin_amdgcn_mfma_f32_16x16x32_f16(
              af[mt][hh], __builtin_bit_cast(f16x8, bf[hh][j]), acc[mt][j], 0, 0, 0);
    // ---- produce gt+1 into other buffer ----
    if (gt < 35) {
      int ib = (buf ^ 1) * 8 + wv * 2;
      *(uint4*)&astage[(ib + 0) * 512 + lane * 8] = bil16(d0[0], d0[1], d0[2], d0[3], wp);
      *(uint4*)&astage[(ib + 1) * 512 + lane * 8] = bil16(d1[0], d1[1], d1[2], d1[3], wp);
      __syncthreads();
    }
  }

  // ---- epilogue: px = p0 + mt*16 + q*4 + r, cout = wv*64 + j*16 + n16; ReLU ----
  float* op = out + (size_t)b * COUT * HW + p0;
  #pragma unroll
  for (int mt = 0; mt < 4; ++mt)
    #pragma unroll
    for (int j = 0; j < 4; ++j) {
      f32x4 v = acc[mt][j];
      #pragma unroll
      for (int r = 0; r < 4; ++r) v[r] = fmaxf(v[r], 0.f);
      int cout = wv * 64 + j * 16 + n16;
      *(f32x4*)(op + (size_t)cout * HW + mt * 16 + q * 4) = v;
    }
}

// ---------------------------------------------------------------------------
extern "C" void kernel_launch(void* const* d_in, const int* in_sizes, int n_in,
                              void* d_out, int out_size, void* d_ws, size_t ws_size,
                              hipStream_t stream) {
  const float* x  = (const float*)d_in[0];
  const float* wo = (const float*)d_in[1];
  const float* bo = (const float*)d_in[2];
  const float* wd = (const float*)d_in[3];
  float* out = (float*)d_out;

  // ws: xt 16,777,216 | wfrag 1,179,648 | wfrag2 40,960 | off 9,437,184
  u16*   xtp    = (u16*)d_ws;
  u16*   wfrag  = (u16*)((char*)d_ws + 16777216);
  u16*   wfrag2 = (u16*)((char*)d_ws + 16777216 + 1179648);
  float* off    = (float*)((char*)d_ws + 16777216 + 1179648 + 40960);

  kprep<<<2192, 256, 0, stream>>>(x, wd, wo, xtp, wfrag, wfrag2);
  k1   <<<512,  256, 0, stream>>>(xtp, wfrag2, bo, off);
  k2   <<<512,  256, 0, stream>>>(xtp, off, wfrag, out);
}

// Round 5
// 198.290 us; speedup vs baseline: 1.6615x; 1.0006x over previous
//
#include <hip/hip_runtime.h>
#include <stdint.h>

// B=2, CIN=256, COUT=256, H=W=128, K=3, G=4
#define HW    16384
#define CIN   256
#define COUT  256
#define Hh    128
#define Ww    128
#define OFFC  72        // G*2*K*K

typedef __attribute__((ext_vector_type(4))) float    f32x4;
typedef __attribute__((ext_vector_type(2))) _Float16 f16x2;
typedef __attribute__((ext_vector_type(8))) _Float16 f16x8;
typedef unsigned short u16;
typedef unsigned int   u32;

__device__ __forceinline__ u16 f2h(float f) { return __builtin_bit_cast(u16, (_Float16)f); }
__device__ __forceinline__ u32 pk2(float f) { u32 h = f2h(f); return h | (h << 16); }
__device__ __forceinline__ f16x2 bch(u32 u) { return __builtin_bit_cast(f16x2, u); }

// ---------------------------------------------------------------------------
// KPREP: fused {x f32 NCHW -> xt f16 [b*4+g][px][64]} + {w_deform -> wfrag f16
// [kc72][nt16][lane64][j8]} + {w_offset -> wfrag2 f16 [kc8][nt5][lane64][j8]}
// ---------------------------------------------------------------------------
__global__ __launch_bounds__(256) void kprep(const float* __restrict__ x, const float* __restrict__ wd,
                                             const float* __restrict__ wo, u16* __restrict__ xt,
                                             u16* __restrict__ wfrag, u16* __restrict__ wfrag2) {
  __shared__ float smem[9216];
  int blk = blockIdx.x;
  if (blk < 2048) {                             // ---- transpose to NHWC f16 ----
    int bg = blk >> 8;
    int p0 = (blk & 255) << 6;
    const float* src = x + (size_t)bg * 64 * HW + p0;
    #pragma unroll
    for (int r = 0; r < 16; ++r) {
      int idx = threadIdx.x + 256 * r;
      int c = idx >> 6, px = idx & 63;
      smem[c * 65 + px] = src[(size_t)c * HW + px];
    }
    __syncthreads();
    int px = threadIdx.x >> 2, seg = threadIdx.x & 3;
    u32 w[8];
    #pragma unroll
    for (int k = 0; k < 8; ++k) {
      float lo = smem[(seg * 16 + 2 * k) * 65 + px];
      float hi = smem[(seg * 16 + 2 * k + 1) * 65 + px];
      w[k] = (u32)f2h(lo) | ((u32)f2h(hi) << 16);
    }
    u16* dst = xt + ((size_t)bg * HW + p0 + px) * 64 + seg * 16;
    *(uint4*)dst       = make_uint4(w[0], w[1], w[2], w[3]);
    *(uint4*)(dst + 8) = make_uint4(w[4], w[5], w[6], w[7]);
  } else if (blk < 2112) {                      // ---- w_deform prepack ----
    int bb = blk - 2048;
    int nt = bb & 15;
    int g  = bb >> 4;
    const float* src = wd + (size_t)(nt * 16) * 2304 + (size_t)g * 64 * 9;
    #pragma unroll
    for (int r = 0; r < 36; ++r) {
      int idx = threadIdx.x + 256 * r;
      int cl  = idx / 576;
      int rem = idx - cl * 576;
      smem[cl * 576 + rem] = src[(size_t)cl * 2304 + rem];
    }
    __syncthreads();
    #pragma unroll
    for (int r = 0; r < 36; ++r) {
      int o    = threadIdx.x + 256 * r;
      int j    = o & 7;
      int lane = (o >> 3) & 63;
      int kcl  = o >> 9;
      int t = kcl >> 1, half = kcl & 1;
      int n = lane & 15, q = lane >> 4;
      int cg = half * 32 + q * 8 + j;
      float v = smem[n * 576 + cg * 9 + t];
      int kc = (g * 9 + t) * 2 + half;
      wfrag[(size_t)((kc * 16 + nt) * 64 + lane) * 8 + j] = f2h(v);
    }
  } else {                                      // ---- w_offset prepack ----
    int e = (blk - 2112) * 256 + threadIdx.x;   // < 20480
    int j = e & 7;
    int lane = (e >> 3) & 63;
    int idx = e >> 9;
    int kc = idx / 5, nt = idx - 5 * kc;
    int n16 = lane & 15, q = lane >> 4;
    int oc = nt * 16 + n16;
    int c  = kc * 32 + q * 8 + j;
    float v = (oc < OFFC) ? wo[(size_t)oc * CIN + c] : 0.f;
    wfrag2[e] = f2h(v);
  }
}

// ---------------------------------------------------------------------------
// K2: fully fused DCN. Block = 4 waves, M=64 px x N=256 cout.
//   Phase 0: in-block offset conv (MFMA) -> offl LDS [gt36][px64][2] f32.
//   Main loop over 36 (g,t): triple-buffered A-stage, one barrier/gt,
//   corners issued 2 gt ahead (rotating reg sets), B prefetched 1 gt ahead.
// ---------------------------------------------------------------------------
__device__ __forceinline__ void mkpre(float yy, float xx, int* ob, u32* wp) {
  float y0f = floorf(yy), x0f = floorf(xx);
  float fy = yy - y0f, fx = xx - x0f;
  int y0 = (int)y0f, x0 = (int)x0f;
  int y1 = y0 + 1, x1 = x0 + 1;
  float vy0 = (y0 >= 0 && y0 < Hh) ? 1.f : 0.f;
  float vy1 = (y1 >= 0 && y1 < Hh) ? 1.f : 0.f;
  float vx0 = (x0 >= 0 && x0 < Ww) ? 1.f : 0.f;
  float vx1 = (x1 >= 0 && x1 < Ww) ? 1.f : 0.f;
  wp[0] = pk2((1.f - fy) * (1.f - fx) * vy0 * vx0);   // zero-pad folded into weights
  wp[1] = pk2((1.f - fy) * fx * vy0 * vx1);
  wp[2] = pk2(fy * (1.f - fx) * vy1 * vx0);
  wp[3] = pk2(fy * fx * vy1 * vx1);
  int cy0 = min(max(y0, 0), Hh - 1), cy1 = min(max(y1, 0), Hh - 1);
  int cx0 = min(max(x0, 0), Ww - 1), cx1 = min(max(x1, 0), Ww - 1);
  ob[0] = (cy0 * Ww + cx0) << 7;                // byte offsets, 128 B pixel records
  ob[1] = (cy0 * Ww + cx1) << 7;
  ob[2] = (cy1 * Ww + cx0) << 7;
  ob[3] = (cy1 * Ww + cx1) << 7;
}

__device__ __forceinline__ uint4 bil16(uint4 a, uint4 b, uint4 c, uint4 d, const u32* wp) {
  f16x2 W0 = bch(wp[0]), W1 = bch(wp[1]), W2 = bch(wp[2]), W3 = bch(wp[3]);
  uint4 r;
  { f16x2 s = bch(a.x) * W0 + bch(b.x) * W1 + bch(c.x) * W2 + bch(d.x) * W3; r.x = __builtin_bit_cast(u32, s); }
  { f16x2 s = bch(a.y) * W0 + bch(b.y) * W1 + bch(c.y) * W2 + bch(d.y) * W3; r.y = __builtin_bit_cast(u32, s); }
  { f16x2 s = bch(a.z) * W0 + bch(b.z) * W1 + bch(c.z) * W2 + bch(d.z) * W3; r.z = __builtin_bit_cast(u32, s); }
  { f16x2 s = bch(a.w) * W0 + bch(b.w) * W1 + bch(c.w) * W2 + bch(d.w) * W3; r.w = __builtin_bit_cast(u32, s); }
  return r;
}

__global__ __launch_bounds__(256, 2) void k2(const u16* __restrict__ xt, const u16* __restrict__ wfrag2,
                                             const float* __restrict__ bo, const u16* __restrict__ wfrag,
                                             float* __restrict__ out) {
  __shared__ u16   astage[3 * 4096];            // 3 bufs x 8 frag-tiles x 512 = 24 KB
  __shared__ float offl[36 * 128];              // [gt][px][{dy,dx}] = 18 KB
  int tid = threadIdx.x;
  int lane = tid & 63, n16 = lane & 15, q = (tid >> 4) & 3;
  int wv = tid >> 6;
  int b  = blockIdx.x >> 8;
  int p0 = (blockIdx.x & 255) << 6;
  int h  = p0 >> 7, w0 = p0 & 127;
  const char* xtb = (const char*)xt + (size_t)b * 4 * HW * 128;

  // ---- phase 0: offset conv for these 64 px (M=16/wave, N=80, K=256) ----
  {
    f32x4 oacc[5];
    #pragma unroll
    for (int nt = 0; nt < 5; ++nt) {
      int oc = nt * 16 + n16;
      float bv = (oc < OFFC) ? bo[oc] : 0.f;
      oacc[nt] = (f32x4){bv, bv, bv, bv};
    }
    #pragma unroll
    for (int kc = 0; kc < 8; ++kc) {
      int g = kc >> 1;
      f16x8 af = __builtin_bit_cast(f16x8, *(const uint4*)(xtb +
          ((size_t)(g * HW + p0 + wv * 16 + n16)) * 128 + (kc & 1) * 64 + q * 16));
      #pragma unroll
      for (int nt = 0; nt < 5; ++nt) {
        f16x8 bf = __builtin_bit_cast(f16x8, *(const uint4*)(wfrag2 + (size_t)(((kc * 5 + nt) << 6) + lane) * 8));
        oacc[nt] = __builtin_amdgcn_mfma_f32_16x16x32_f16(af, bf, oacc[nt], 0, 0, 0);
      }
    }
    #pragma unroll
    for (int nt = 0; nt < 5; ++nt) {
      int oc = nt * 16 + n16;
      if (oc < OFFC) {
        int gt = oc >> 1, comp = oc & 1;
        #pragma unroll
        for (int r = 0; r < 4; ++r)
          offl[(gt * 64 + wv * 16 + q * 4 + r) * 2 + comp] = oacc[nt][r];
      }
    }
  }
  __syncthreads();

  float fh = (float)h;
  float fx = (float)(w0 + wv * 16 + n16);
  int chb = q * 16;
  int pxl = wv * 16 + n16;

  f32x4 acc[4][4];
  #pragma unroll
  for (int mt = 0; mt < 4; ++mt)
    #pragma unroll
    for (int j = 0; j < 4; ++j) acc[mt][j] = (f32x4){0.f, 0.f, 0.f, 0.f};

  auto issue = [&](int gt, uint4* d, u32* wp) {          // start corner loads for gt
    float2 o = *(const float2*)&offl[(gt * 64 + pxl) * 2];
    int g = (gt * 57) >> 9;                              // gt/9
    int t = gt - g * 9;
    int i = (t * 683) >> 11;                             // t/3
    int j = t - i * 3;
    int ob[4];
    mkpre(fh + (float)(i - 1) + o.x, fx + (float)(j - 1) + o.y, ob, wp);
    const char* xg = xtb + (size_t)g * HW * 128;
    #pragma unroll
    for (int c = 0; c < 4; ++c) {
      d[c]     = *(const uint4*)(xg + ob[c] + chb);
      d[4 + c] = *(const uint4*)(xg + ob[c] + chb + 64);
    }
  };
  auto produce = [&](int slot, const uint4* d, const u32* wp) {
    *(uint4*)&astage[(slot * 8 + wv * 2 + 0) * 512 + lane * 8] = bil16(d[0], d[1], d[2], d[3], wp);
    *(uint4*)&astage[(slot * 8 + wv * 2 + 1) * 512 + lane * 8] = bil16(d[4], d[5], d[6], d[7], wp);
  };
  auto loadB = [&](int gt, uint4* bf) {
    const u16* wb = wfrag + (size_t)gt * 16384 + (size_t)(wv * 4) * 512 + (size_t)lane * 8;
    #pragma unroll
    for (int hh = 0; hh < 2; ++hh)
      #pragma unroll
      for (int j = 0; j < 4; ++j)
        bf[hh * 4 + j] = *(const uint4*)(wb + (size_t)(hh * 16 + j) * 512);
  };
  auto consume = [&](int slot, const uint4* bf) {
    #pragma unroll
    for (int hh = 0; hh < 2; ++hh) {
      f16x8 af[4];
      #pragma unroll
      for (int mt = 0; mt < 4; ++mt)
        af[mt] = __builtin_bit_cast(f16x8,
            *(const uint4*)&astage[(slot * 8 + mt * 2 + hh) * 512 + lane * 8]);
      #pragma unroll
      for (int mt = 0; mt < 4; ++mt)
        #pragma unroll
        for (int j = 0; j < 4; ++j)
          acc[mt][j] = __builtin_amdgcn_mfma_f32_16x16x32_f16(
              af[mt], __builtin_bit_cast(f16x8, bf[hh * 4 + j]), acc[mt][j], 0, 0, 0);
    }
  };

  // ---- pipeline prologue ----
  uint4 dA[8], dB[8];
  u32   wpA[4], wpB[4];
  uint4 bfA[8], bfB[8];
  issue(0, dA, wpA);                            // set parity: gt even -> A, odd -> B
  issue(1, dB, wpB);
  produce(0, dA, wpA);
  loadB(0, bfA);
  __syncthreads();

  // ---- main loop: half(gt) = produce(gt+1); issue(gt+2); loadB(gt+1); barrier; consume(gt) ----
  #pragma unroll 1
  for (int gt = 0; gt < 36; gt += 2) {
    // even half (consume gt; gt+1 data in B-set; issue gt+2 into A-set)
    produce((gt + 1) % 3, dB, wpB);
    if (gt + 2 < 36) issue(gt + 2, dA, wpA);
    loadB(gt + 1, bfB);
    __syncthreads();
    consume(gt % 3, bfA);
    // odd half (consume gt+1; issue gt+3 into B-set)
    if (gt + 2 < 36) {
      produce((gt + 2) % 3, dA, wpA);
      if (gt + 3 < 36) issue(gt + 3, dB, wpB);
      loadB(gt + 2, bfA);
      __syncthreads();
    }
    consume((gt + 1) % 3, bfB);
  }

  // ---- epilogue: px = p0 + mt*16 + q*4 + r, cout = wv*64 + j*16 + n16; ReLU ----
  float* op = out + (size_t)b * COUT * HW + p0;
  #pragma unroll
  for (int mt = 0; mt < 4; ++mt)
    #pragma unroll
    for (int j = 0; j < 4; ++j) {
      f32x4 v = acc[mt][j];
      #pragma unroll
      for (int r = 0; r < 4; ++r) v[r] = fmaxf(v[r], 0.f);
      int cout = wv * 64 + j * 16 + n16;
      *(f32x4*)(op + (size_t)cout * HW + mt * 16 + q * 4) = v;
    }
}

// ---------------------------------------------------------------------------
extern "C" void kernel_launch(void* const* d_in, const int* in_sizes, int n_in,
                              void* d_out, int out_size, void* d_ws, size_t ws_size,
                              hipStream_t stream) {
  const float* x  = (const float*)d_in[0];
  const float* wo = (const float*)d_in[1];
  const float* bo = (const float*)d_in[2];
  const float* wd = (const float*)d_in[3];
  float* out = (float*)d_out;

  // ws: xt 16,777,216 | wfrag 1,179,648 | wfrag2 40,960
  u16* xtp    = (u16*)d_ws;
  u16* wfrag  = (u16*)((char*)d_ws + 16777216);
  u16* wfrag2 = (u16*)((char*)d_ws + 16777216 + 1179648);

  kprep<<<2192, 256, 0, stream>>>(x, wd, wo, xtp, wfrag, wfrag2);
  k2   <<<512,  256, 0, stream>>>(xtp, wfrag2, bo, wfrag, out);
}